// Round 4
// baseline (2758.192 us; speedup 1.0000x reference)
//
#include <hip/hip_runtime.h>
#include <hip/hip_bf16.h>
#include <math.h>

typedef __hip_bfloat16 bf16;

__device__ __forceinline__ float ldf(float v) { return v; }
__device__ __forceinline__ float ldf(bf16 v) { return __bfloat162float(v); }

template <typename T> __device__ __forceinline__ T fromf(float v);
template <> __device__ __forceinline__ float fromf<float>(float v) { return v; }
template <> __device__ __forceinline__ bf16 fromf<bf16>(float v) { return __float2bfloat16(v); }

// ---------------- DCT matrix: fp64 build, single rounding to fp32 ----------------
// matches np: cos(pi*(2i+1)*k/512)*sqrt(2/256) in f64, row0 *= sqrt(0.5), cast f32
__global__ void k_build_dct(float* __restrict__ D) {
  int k = blockIdx.x, i = threadIdx.x;
  double v = cos(3.14159265358979323846 * (2.0 * i + 1.0) * (double)k / 512.0) *
             0.08838834764831845;
  if (k == 0) v *= 0.7071067811865476;
  D[k * 256 + i] = (float)v;
}

// ---- stage1: M1[bc] = D @ X[bc], fp32, per-element single accumulator, j ascending (BLAS order) ----
__global__ __launch_bounds__(256) void k_dct1(const float* __restrict__ D,
                                              const float* __restrict__ x,
                                              float* __restrict__ M1) {
  __shared__ float As[32][33];
  __shared__ float Bs[32][33];
  int tid = threadIdx.x;
  int tx = tid & 31, ty = tid >> 5;
  int k0 = blockIdx.x * 32, i0 = blockIdx.y * 32;
  size_t base = (size_t)blockIdx.z * 65536;
  float acc[4] = {0.f, 0.f, 0.f, 0.f};
  for (int kk = 0; kk < 256; kk += 32) {
    for (int l = tid; l < 1024; l += 256) {
      int r = l >> 5, c = l & 31;
      As[r][c] = D[(i0 + r) * 256 + kk + c];
      Bs[r][c] = x[base + (size_t)(kk + r) * 256 + k0 + c];
    }
    __syncthreads();
#pragma unroll
    for (int j = 0; j < 32; ++j) {
      float bv = Bs[j][tx];
#pragma unroll
      for (int q = 0; q < 4; ++q) acc[q] = fmaf(As[ty + 8 * q][j], bv, acc[q]);
    }
    __syncthreads();
  }
#pragma unroll
  for (int q = 0; q < 4; ++q)
    M1[base + (size_t)(i0 + ty + 8 * q) * 256 + k0 + tx] = acc[q];
}

// ---- stage2: xf = lognorm(M1 @ D^T), fp32, k ascending, single accumulator ----
__global__ __launch_bounds__(256) void k_dct2(const float* __restrict__ M1,
                                              const float* __restrict__ D,
                                              const float* __restrict__ dmean,
                                              const float* __restrict__ dstd,
                                              float* __restrict__ xf) {
  __shared__ float As[32][33];
  __shared__ float Bs[32][33];
  int tid = threadIdx.x;
  int tx = tid & 31, ty = tid >> 5;
  int l0 = blockIdx.x * 32, i0 = blockIdx.y * 32;
  int bc = blockIdx.z;
  size_t base = (size_t)bc * 65536;
  int ch = bc % 3;
  float acc[4] = {0.f, 0.f, 0.f, 0.f};
  for (int kk = 0; kk < 256; kk += 32) {
    for (int l = tid; l < 1024; l += 256) {
      int r = l >> 5, c = l & 31;
      As[r][c] = M1[base + (size_t)(i0 + r) * 256 + kk + c];
      Bs[c][r] = D[(l0 + r) * 256 + kk + c];  // Bs[j][t] = D[l0+t][kk+j]
    }
    __syncthreads();
#pragma unroll
    for (int j = 0; j < 32; ++j) {
      float bv = Bs[j][tx];
#pragma unroll
      for (int q = 0; q < 4; ++q) acc[q] = fmaf(As[ty + 8 * q][j], bv, acc[q]);
    }
    __syncthreads();
  }
#pragma unroll
  for (int q = 0; q < 4; ++q) {
    int ii = i0 + ty + 8 * q, ll = l0 + tx;
    float lf = logf(fabsf(acc[q]) + 1e-13f);
    int mi = (ch * 256 + ii) * 256 + ll;
    xf[base + (size_t)ii * 256 + ll] = (lf - dmean[mi]) / dstd[mi];
  }
}

// ------- front conv (3->32, two branches) + bn0 + relu, fp32 out -------
__global__ __launch_bounds__(256) void k_conv_front(
    const float* __restrict__ x, const float* __restrict__ xf,
    const float* __restrict__ w_spa, const float* __restrict__ b_spa,
    const float* __restrict__ w_fre, const float* __restrict__ b_fre,
    const float* __restrict__ g, const float* __restrict__ bb,
    const float* __restrict__ m, const float* __restrict__ vv,
    float* __restrict__ feat) {
  int z = blockIdx.z;
  const float* in = z ? xf : x;
  const float* w = z ? w_fre : w_spa;
  const float* bias = z ? b_fre : b_spa;
  __shared__ float wl[864];
  __shared__ float sc[32], sh[32];
  int tid = threadIdx.x;
  for (int i = tid; i < 864; i += 256) wl[i] = w[i];
  if (tid < 32) {
    int cg = z * 32 + tid;
    float s = g[cg] * rsqrtf(vv[cg] + 1e-5f);
    sc[tid] = s;
    sh[tid] = (bias[tid] - m[cg]) * s + bb[cg];
  }
  __syncthreads();
  int b = blockIdx.y;
  int idx = blockIdx.x * 256 + tid;
  int ry = idx >> 8;
  int xx = idx & 255;
  int y0 = ry * 2;
  const float* inb = in + (size_t)b * 3 * 65536;
  float a0[32], a1[32];
#pragma unroll
  for (int co = 0; co < 32; ++co) {
    a0[co] = 0.f;
    a1[co] = 0.f;
  }
  for (int ci = 0; ci < 3; ++ci) {
    const float* p = inb + (size_t)ci * 65536;
    float v[4][3];
#pragma unroll
    for (int r = 0; r < 4; ++r) {
      int iy = y0 + r - 1;
      bool yok = (unsigned)iy < 256u;
#pragma unroll
      for (int c = 0; c < 3; ++c) {
        int ix = xx + c - 1;
        v[r][c] = (yok && (unsigned)ix < 256u) ? p[iy * 256 + ix] : 0.f;
      }
    }
#pragma unroll
    for (int t9 = 0; t9 < 9; ++t9) {
      int ky = t9 / 3, kx = t9 % 3;
      float v0 = v[ky][kx], v1 = v[ky + 1][kx];
#pragma unroll
      for (int co = 0; co < 32; ++co) {
        float wv = wl[co * 27 + ci * 9 + t9];
        a0[co] = fmaf(v0, wv, a0[co]);
        a1[co] = fmaf(v1, wv, a1[co]);
      }
    }
  }
#pragma unroll
  for (int co = 0; co < 32; ++co) {
    size_t o = ((size_t)(b * 64 + z * 32 + co) * 256 + y0) * 256 + xx;
    float r0 = a0[co] * sc[co] + sh[co];
    float r1 = a1[co] * sc[co] + sh[co];
    feat[o] = r0 > 0.f ? r0 : 0.f;
    feat[o + 256] = r1 > 0.f ? r1 : 0.f;
  }
}

// ---------------- generic conv3x3 (CI -> 32) + BN + relu -------------
template <int CI, typename Tin, typename Tout>
__global__ __launch_bounds__(256) void k_conv(
    const Tin* __restrict__ in, const float* __restrict__ w,
    const float* __restrict__ bias, const float* __restrict__ g,
    const float* __restrict__ bb, const float* __restrict__ m,
    const float* __restrict__ vv, Tout* __restrict__ out, int H, int W) {
  __shared__ __align__(16) float wl[32 * 32 * 12];
  __shared__ float sc[32], sh[32];
  int tid = threadIdx.x;
  if (tid < 32) {
    float s = g[tid] * rsqrtf(vv[tid] + 1e-5f);
    sc[tid] = s;
    sh[tid] = (bias[tid] - m[tid]) * s + bb[tid];
  }
  int b = blockIdx.y;
  int idx = blockIdx.x * 256 + tid;
  int ry = idx / W;
  int xx = idx - ry * W;
  int y0 = ry * 2;
  int HW = H * W;
  const Tin* inb = in + (size_t)b * CI * HW;
  float a[2][32];
#pragma unroll
  for (int r = 0; r < 2; ++r)
#pragma unroll
    for (int co = 0; co < 32; ++co) a[r][co] = 0.f;

  for (int cb = 0; cb < CI; cb += 32) {
    __syncthreads();
    for (int i2 = tid; i2 < 9216; i2 += 256) {
      int co = i2 / 288;
      int rem = i2 - co * 288;
      int cip = rem / 9, k = rem - cip * 9;
      wl[(co * 32 + cip) * 12 + k] = w[(co * CI + cb) * 9 + rem];
    }
    __syncthreads();
    for (int cip = 0; cip < 32; ++cip) {
      const Tin* p = inb + (size_t)(cb + cip) * HW;
      float v[4][3];
#pragma unroll
      for (int r = 0; r < 4; ++r) {
        int iy = y0 + r - 1;
        bool yok = (unsigned)iy < (unsigned)H;
#pragma unroll
        for (int c = 0; c < 3; ++c) {
          int ix = xx + c - 1;
          v[r][c] = (yok && (unsigned)ix < (unsigned)W) ? ldf(p[iy * W + ix]) : 0.f;
        }
      }
#pragma unroll
      for (int co = 0; co < 32; ++co) {
        const float4 wA = *(const float4*)&wl[(co * 32 + cip) * 12];
        const float4 wB = *(const float4*)&wl[(co * 32 + cip) * 12 + 4];
        const float w8 = wl[(co * 32 + cip) * 12 + 8];
        float wv[9] = {wA.x, wA.y, wA.z, wA.w, wB.x, wB.y, wB.z, wB.w, w8};
#pragma unroll
        for (int t9 = 0; t9 < 9; ++t9) {
          int ky = t9 / 3, kx = t9 % 3;
          a[0][co] = fmaf(v[ky][kx], wv[t9], a[0][co]);
          a[1][co] = fmaf(v[ky + 1][kx], wv[t9], a[1][co]);
        }
      }
    }
  }
#pragma unroll
  for (int co = 0; co < 32; ++co) {
    float s = sc[co], h0 = sh[co];
#pragma unroll
    for (int r = 0; r < 2; ++r) {
      float val = a[r][co] * s + h0;
      out[((size_t)(b * 32 + co) * H + (y0 + r)) * W + xx] =
          fromf<Tout>(val > 0.f ? val : 0.f);
    }
  }
}

// ---------------- 2x2 avg pool ----------------
__global__ __launch_bounds__(256) void k_pool2(const bf16* __restrict__ in,
                                               bf16* __restrict__ out, int Ho,
                                               int Wo) {
  int t = blockIdx.x * 256 + threadIdx.x;
  int Wi = Wo * 2;
  int plane_o = Ho * Wo;
  int p = t / plane_o;
  int rem = t - p * plane_o;
  int y = rem / Wo, x2 = rem - y * Wo;
  const bf16* pi = in + (size_t)p * plane_o * 4 + (size_t)(2 * y) * Wi + 2 * x2;
  float s = ldf(pi[0]) + ldf(pi[1]) + ldf(pi[Wi]) + ldf(pi[Wi + 1]);
  out[t] = __float2bfloat16(0.25f * s);
}

// ---------------- global mean over 32x32 ----------------
__global__ __launch_bounds__(256) void k_gmean(const bf16* __restrict__ in,
                                               float* __restrict__ meanbuf) {
  int b = blockIdx.x, c = blockIdx.y;
  const bf16* p = in + (size_t)(b * 32 + c) * 1024;
  float s = 0.f;
  for (int j = threadIdx.x; j < 1024; j += 256) s += ldf(p[j]);
  for (int o = 32; o > 0; o >>= 1) s += __shfl_down(s, o, 64);
  __shared__ float ls[4];
  int wid = threadIdx.x >> 6;
  if ((threadIdx.x & 63) == 0) ls[wid] = s;
  __syncthreads();
  if (threadIdx.x == 0)
    meanbuf[b * 32 + c] = (ls[0] + ls[1] + ls[2] + ls[3]) * (1.f / 1024.f);
}

// ---------------- fc (fp32 logits out) ----------------
__global__ void k_fc(const float* __restrict__ meanbuf,
                     const float* __restrict__ fw, const float* __restrict__ fb,
                     float* __restrict__ logits) {
  int t = threadIdx.x;
  if (t < 32) {
    int b = t >> 1, o = t & 1;
    float s = fb[o];
    for (int c = 0; c < 32; ++c) s = fmaf(meanbuf[b * 32 + c], fw[o * 32 + c], s);
    logits[t] = s;
  }
}

extern "C" void kernel_launch(void* const* d_in, const int* in_sizes, int n_in,
                              void* d_out, int out_size, void* d_ws,
                              size_t ws_size, hipStream_t stream) {
  const float* x = (const float*)d_in[0];
  const float* dmean = (const float*)d_in[1];
  const float* dstd = (const float*)d_in[2];
  const float* w_spa = (const float*)d_in[3];
  const float* b_spa = (const float*)d_in[4];
  const float* w_fre = (const float*)d_in[5];
  const float* b_fre = (const float*)d_in[6];
  const float* bn0_g = (const float*)d_in[7];
  const float* bn0_b = (const float*)d_in[8];
  const float* bn0_m = (const float*)d_in[9];
  const float* bn0_v = (const float*)d_in[10];
  const float* cls_w1 = (const float*)d_in[11];
  const float* cls_b1 = (const float*)d_in[12];
  const float* cls_w = (const float*)d_in[13];
  const float* cls_b = (const float*)d_in[14];
  const float* cbn_g = (const float*)d_in[15];
  const float* cbn_b = (const float*)d_in[16];
  const float* cbn_m = (const float*)d_in[17];
  const float* cbn_v = (const float*)d_in[18];
  const float* fc_w = (const float*)d_in[19];
  const float* fc_b = (const float*)d_in[20];

  float* out = (float*)d_out;
  float* logits = out;     // [16,2] fp32
  float* feat = out + 32;  // [16,64,256,256] fp32

  char* ws = (char*)d_ws;
  float* D = (float*)ws;                         // 256 KB
  float* M1 = (float*)(ws + (1u << 20));         // 12.6 MB (1MB..13.6MB)
  float* xf = (float*)(ws + (16u << 20));        // 12.6 MB (16MB..28.6MB)
  bf16* bufA = (bf16*)ws;                        // 64 MB (clobbers D/M1/xf when dead)
  bf16* bufB = (bf16*)(ws + (64u << 20));        // 64 MB
  float* meanbuf = (float*)(ws + (64u << 20));   // 512 B at bufB base (dead after L10)

  // DCT branch (fp32, BLAS-order accumulation)
  k_build_dct<<<dim3(256), dim3(256), 0, stream>>>(D);
  k_dct1<<<dim3(8, 8, 48), dim3(256), 0, stream>>>(D, x, M1);
  k_dct2<<<dim3(8, 8, 48), dim3(256), 0, stream>>>(M1, D, dmean, dstd, xf);

  // front convs + bn0 + relu -> feature_map (output 1, fp32)
  k_conv_front<<<dim3(128, 16, 2), dim3(256), 0, stream>>>(
      x, xf, w_spa, b_spa, w_fre, b_fre, bn0_g, bn0_b, bn0_m, bn0_v, feat);

  const int WS = 32 * 32 * 9;
  // L1 (64->32) @256, fp32 in -> bf16 out
  k_conv<64, float, bf16><<<dim3(128, 16), dim3(256), 0, stream>>>(
      feat, cls_w1, cls_b1, cbn_g, cbn_b, cbn_m, cbn_v, bufA, 256, 256);
  // L2: A->B @256
  k_conv<32, bf16, bf16><<<dim3(128, 16), dim3(256), 0, stream>>>(
      bufA, cls_w + 0 * WS, cls_b + 0 * 32, cbn_g + 32, cbn_b + 32, cbn_m + 32,
      cbn_v + 32, bufB, 256, 256);
  // L3: B->A @256
  k_conv<32, bf16, bf16><<<dim3(128, 16), dim3(256), 0, stream>>>(
      bufB, cls_w + 1 * WS, cls_b + 1 * 32, cbn_g + 64, cbn_b + 64, cbn_m + 64,
      cbn_v + 64, bufA, 256, 256);
  // L4: A->B @256, pool -> A @128
  k_conv<32, bf16, bf16><<<dim3(128, 16), dim3(256), 0, stream>>>(
      bufA, cls_w + 2 * WS, cls_b + 2 * 32, cbn_g + 96, cbn_b + 96, cbn_m + 96,
      cbn_v + 96, bufB, 256, 256);
  k_pool2<<<dim3(32768), dim3(256), 0, stream>>>(bufB, bufA, 128, 128);
  // L5: A->B @128
  k_conv<32, bf16, bf16><<<dim3(32, 16), dim3(256), 0, stream>>>(
      bufA, cls_w + 3 * WS, cls_b + 3 * 32, cbn_g + 128, cbn_b + 128,
      cbn_m + 128, cbn_v + 128, bufB, 128, 128);
  // L6: B->A @128, pool -> B @64
  k_conv<32, bf16, bf16><<<dim3(32, 16), dim3(256), 0, stream>>>(
      bufB, cls_w + 4 * WS, cls_b + 4 * 32, cbn_g + 160, cbn_b + 160,
      cbn_m + 160, cbn_v + 160, bufA, 128, 128);
  k_pool2<<<dim3(8192), dim3(256), 0, stream>>>(bufA, bufB, 64, 64);
  // L7: B->A @64
  k_conv<32, bf16, bf16><<<dim3(8, 16), dim3(256), 0, stream>>>(
      bufB, cls_w + 5 * WS, cls_b + 5 * 32, cbn_g + 192, cbn_b + 192,
      cbn_m + 192, cbn_v + 192, bufA, 64, 64);
  // L8: A->B @64, pool -> A @32
  k_conv<32, bf16, bf16><<<dim3(8, 16), dim3(256), 0, stream>>>(
      bufA, cls_w + 6 * WS, cls_b + 6 * 32, cbn_g + 224, cbn_b + 224,
      cbn_m + 224, cbn_v + 224, bufB, 64, 64);
  k_pool2<<<dim3(2048), dim3(256), 0, stream>>>(bufB, bufA, 32, 32);
  // L9: A->B @32
  k_conv<32, bf16, bf16><<<dim3(2, 16), dim3(256), 0, stream>>>(
      bufA, cls_w + 7 * WS, cls_b + 7 * 32, cbn_g + 256, cbn_b + 256,
      cbn_m + 256, cbn_v + 256, bufB, 32, 32);
  // L10: B->A @32
  k_conv<32, bf16, bf16><<<dim3(2, 16), dim3(256), 0, stream>>>(
      bufB, cls_w + 8 * WS, cls_b + 8 * 32, cbn_g + 288, cbn_b + 288,
      cbn_m + 288, cbn_v + 288, bufA, 32, 32);

  // global mean + fc
  k_gmean<<<dim3(16, 32), dim3(256), 0, stream>>>(bufA, meanbuf);
  k_fc<<<dim3(1), dim3(64), 0, stream>>>(meanbuf, fc_w, fc_b, logits);
}

// Round 5
// 859.056 us; speedup vs baseline: 3.2107x; 3.2107x over previous
//
#include <hip/hip_runtime.h>
#include <hip/hip_bf16.h>
#include <math.h>

typedef __hip_bfloat16 bf16;
typedef __attribute__((ext_vector_type(8))) short short8;
typedef __attribute__((ext_vector_type(4))) float f32x4;

__device__ __forceinline__ float b2f(short s) {
  unsigned u = ((unsigned)(unsigned short)s) << 16;
  return __builtin_bit_cast(float, u);
}
__device__ __forceinline__ short f2b(float f) {
  bf16 h = __float2bfloat16(f);
  return *reinterpret_cast<short*>(&h);
}

// ---------------- DCT matrix: fp64 build, single rounding to fp32 ----------------
__global__ void k_build_dct(float* __restrict__ D) {
  int k = blockIdx.x, i = threadIdx.x;
  double v = cos(3.14159265358979323846 * (2.0 * i + 1.0) * (double)k / 512.0) *
             0.08838834764831845;
  if (k == 0) v *= 0.7071067811865476;
  D[k * 256 + i] = (float)v;
}

// ---- stage1: M1[bc] = D @ X[bc], fp32 single accumulator, k ascending ----
__global__ __launch_bounds__(256) void k_dct1(const float* __restrict__ D,
                                              const float* __restrict__ x,
                                              float* __restrict__ M1) {
  __shared__ float As[32][33];
  __shared__ float Bs[32][33];
  int tid = threadIdx.x;
  int tx = tid & 31, ty = tid >> 5;
  int k0 = blockIdx.x * 32, i0 = blockIdx.y * 32;
  size_t base = (size_t)blockIdx.z * 65536;
  float acc[4] = {0.f, 0.f, 0.f, 0.f};
  for (int kk = 0; kk < 256; kk += 32) {
    for (int l = tid; l < 1024; l += 256) {
      int r = l >> 5, c = l & 31;
      As[r][c] = D[(i0 + r) * 256 + kk + c];
      Bs[r][c] = x[base + (size_t)(kk + r) * 256 + k0 + c];
    }
    __syncthreads();
#pragma unroll
    for (int j = 0; j < 32; ++j) {
      float bv = Bs[j][tx];
#pragma unroll
      for (int q = 0; q < 4; ++q) acc[q] = fmaf(As[ty + 8 * q][j], bv, acc[q]);
    }
    __syncthreads();
  }
#pragma unroll
  for (int q = 0; q < 4; ++q)
    M1[base + (size_t)(i0 + ty + 8 * q) * 256 + k0 + tx] = acc[q];
}

// ---- stage2: xf = lognorm(M1 @ D^T) ----
__global__ __launch_bounds__(256) void k_dct2(const float* __restrict__ M1,
                                              const float* __restrict__ D,
                                              const float* __restrict__ dmean,
                                              const float* __restrict__ dstd,
                                              float* __restrict__ xf) {
  __shared__ float As[32][33];
  __shared__ float Bs[32][33];
  int tid = threadIdx.x;
  int tx = tid & 31, ty = tid >> 5;
  int l0 = blockIdx.x * 32, i0 = blockIdx.y * 32;
  int bc = blockIdx.z;
  size_t base = (size_t)bc * 65536;
  int ch = bc % 3;
  float acc[4] = {0.f, 0.f, 0.f, 0.f};
  for (int kk = 0; kk < 256; kk += 32) {
    for (int l = tid; l < 1024; l += 256) {
      int r = l >> 5, c = l & 31;
      As[r][c] = M1[base + (size_t)(i0 + r) * 256 + kk + c];
      Bs[c][r] = D[(l0 + r) * 256 + kk + c];
    }
    __syncthreads();
#pragma unroll
    for (int j = 0; j < 32; ++j) {
      float bv = Bs[j][tx];
#pragma unroll
      for (int q = 0; q < 4; ++q) acc[q] = fmaf(As[ty + 8 * q][j], bv, acc[q]);
    }
    __syncthreads();
  }
#pragma unroll
  for (int q = 0; q < 4; ++q) {
    int ii = i0 + ty + 8 * q, ll = l0 + tx;
    float lf = logf(fabsf(acc[q]) + 1e-13f);
    int mi = (ch * 256 + ii) * 256 + ll;
    xf[base + (size_t)ii * 256 + ll] = (lf - dmean[mi]) / dstd[mi];
  }
}

// ------- front conv (3->32, two branches) + bn0 + relu, fp32 NCHW out -------
__global__ __launch_bounds__(256) void k_conv_front(
    const float* __restrict__ x, const float* __restrict__ xf,
    const float* __restrict__ w_spa, const float* __restrict__ b_spa,
    const float* __restrict__ w_fre, const float* __restrict__ b_fre,
    const float* __restrict__ g, const float* __restrict__ bb,
    const float* __restrict__ m, const float* __restrict__ vv,
    float* __restrict__ feat) {
  int z = blockIdx.z;
  const float* in = z ? xf : x;
  const float* w = z ? w_fre : w_spa;
  const float* bias = z ? b_fre : b_spa;
  __shared__ float wl[864];
  __shared__ float sc[32], sh[32];
  int tid = threadIdx.x;
  for (int i = tid; i < 864; i += 256) wl[i] = w[i];
  if (tid < 32) {
    int cg = z * 32 + tid;
    float s = g[cg] * rsqrtf(vv[cg] + 1e-5f);
    sc[tid] = s;
    sh[tid] = (bias[tid] - m[cg]) * s + bb[cg];
  }
  __syncthreads();
  int b = blockIdx.y;
  int idx = blockIdx.x * 256 + tid;
  int ry = idx >> 8;
  int xx = idx & 255;
  int y0 = ry * 2;
  const float* inb = in + (size_t)b * 3 * 65536;
  float a0[32], a1[32];
#pragma unroll
  for (int co = 0; co < 32; ++co) {
    a0[co] = 0.f;
    a1[co] = 0.f;
  }
  for (int ci = 0; ci < 3; ++ci) {
    const float* p = inb + (size_t)ci * 65536;
    float v[4][3];
#pragma unroll
    for (int r = 0; r < 4; ++r) {
      int iy = y0 + r - 1;
      bool yok = (unsigned)iy < 256u;
#pragma unroll
      for (int c = 0; c < 3; ++c) {
        int ix = xx + c - 1;
        v[r][c] = (yok && (unsigned)ix < 256u) ? p[iy * 256 + ix] : 0.f;
      }
    }
#pragma unroll
    for (int t9 = 0; t9 < 9; ++t9) {
      int ky = t9 / 3, kx = t9 % 3;
      float v0 = v[ky][kx], v1 = v[ky + 1][kx];
#pragma unroll
      for (int co = 0; co < 32; ++co) {
        float wv = wl[co * 27 + ci * 9 + t9];
        a0[co] = fmaf(v0, wv, a0[co]);
        a1[co] = fmaf(v1, wv, a1[co]);
      }
    }
  }
#pragma unroll
  for (int co = 0; co < 32; ++co) {
    size_t o = ((size_t)(b * 64 + z * 32 + co) * 256 + y0) * 256 + xx;
    float r0 = a0[co] * sc[co] + sh[co];
    float r1 = a1[co] * sc[co] + sh[co];
    feat[o] = r0 > 0.f ? r0 : 0.f;
    feat[o + 256] = r1 > 0.f ? r1 : 0.f;
  }
}

// ---------------- MFMA conv3x3 32->32, NHWC bf16 in/out ----------------
// wave: A=weights (M=co 2x16), B=pixels (N=16), K=32 cin per tap.
template <int TX>
__global__ __launch_bounds__(256) void k_conv_mfma(
    const short* __restrict__ in,  // NHWC [B][H][W][32] bf16
    const float* __restrict__ w,   // [32][32][3][3] fp32
    const float* __restrict__ bias, const float* __restrict__ g,
    const float* __restrict__ bb, const float* __restrict__ m,
    const float* __restrict__ vv,
    short* __restrict__ out, int H) {
  constexpr int XT = TX + 2;
  constexpr int NXT = TX / 16;
  constexpr int NR = (NXT == 4) ? 2 : 1;
  __shared__ short tile[4 * XT * 32];
  __shared__ short wlds[9216];
  __shared__ float sc[32], sh[32];
  int tid = threadIdx.x;
  int lane = tid & 63, wid = tid >> 6;
  int W = H;
  int b = blockIdx.z, y0 = blockIdx.y * 2, x0 = blockIdx.x * TX;
  if (tid < 32) {
    float s = g[tid] * rsqrtf(vv[tid] + 1e-5f);
    sc[tid] = s;
    sh[tid] = (bias[tid] - m[tid]) * s + bb[tid];
  }
  // stage input tile rows y0-1..y0+2 (coalesced b128 copies)
  for (int ir = 0; ir < 4; ++ir) {
    int gy = y0 - 1 + ir;
    bool yok = (unsigned)gy < (unsigned)H;
    for (int ch = tid; ch < XT * 4; ch += 256) {
      int xl = ch >> 2, cg = ch & 3;
      int gx = x0 - 1 + xl;
      short8 v = {0, 0, 0, 0, 0, 0, 0, 0};
      if (yok && (unsigned)gx < (unsigned)W)
        v = *(const short8*)(in + ((((size_t)(b * H + gy) * W + gx)) << 5) + cg * 8);
      *(short8*)&tile[(ir * XT + xl) * 32 + cg * 8] = v;
    }
  }
  // stage weights fp32->bf16 [tap][co][cin] (src-coalesced)
  for (int s = tid; s < 9216; s += 256) {
    int co = s / 288, rem = s - co * 288;
    int cin = rem / 9, tap = rem - cin * 9;
    wlds[tap * 1024 + co * 32 + cin] = f2b(w[s]);
  }
  __syncthreads();
  int px = lane & 15, g4 = lane >> 4;
  int RB = (NXT == 4) ? 0 : (wid >> 1);
  int wx = (NXT == 4) ? wid : (wid & 1);
  short8 wf[9][2];
#pragma unroll
  for (int tap = 0; tap < 9; ++tap)
#pragma unroll
    for (int ct = 0; ct < 2; ++ct)
      wf[tap][ct] = *(short8*)&wlds[tap * 1024 + (ct * 16 + px) * 32 + g4 * 8];
  f32x4 acc[NR][2];
#pragma unroll
  for (int r = 0; r < NR; ++r)
#pragma unroll
    for (int ct = 0; ct < 2; ++ct) acc[r][ct] = {0.f, 0.f, 0.f, 0.f};
#pragma unroll
  for (int dx = 0; dx < 3; ++dx) {
    short8 fr[NR + 2];
#pragma unroll
    for (int ir = 0; ir < NR + 2; ++ir)
      fr[ir] = *(short8*)&tile[((RB + ir) * XT + wx * 16 + px + dx) * 32 + g4 * 8];
#pragma unroll
    for (int dy = 0; dy < 3; ++dy)
#pragma unroll
      for (int r = 0; r < NR; ++r)
#pragma unroll
        for (int ct = 0; ct < 2; ++ct)
          acc[r][ct] = __builtin_amdgcn_mfma_f32_16x16x32_bf16(
              wf[dy * 3 + dx][ct], fr[r + dy], acc[r][ct], 0, 0, 0);
  }
#pragma unroll
  for (int r = 0; r < NR; ++r) {
    int y = y0 + RB + r;
    int xg = x0 + wx * 16 + px;
    size_t ob = (((size_t)(b * H + y) * W + xg) << 5);
#pragma unroll
    for (int ct = 0; ct < 2; ++ct) {
      unsigned short u[4];
#pragma unroll
      for (int q = 0; q < 4; ++q) {
        int co = ct * 16 + g4 * 4 + q;
        float val = acc[r][ct][q] * sc[co] + sh[co];
        val = val > 0.f ? val : 0.f;
        u[q] = (unsigned short)f2b(val);
      }
      uint2 pk;
      pk.x = (unsigned)u[0] | ((unsigned)u[1] << 16);
      pk.y = (unsigned)u[2] | ((unsigned)u[3] << 16);
      *(uint2*)(out + ob + ct * 16 + g4 * 4) = pk;
    }
  }
}

// ---------------- MFMA conv L1: 64ch fp32 NCHW in -> 32ch NHWC bf16 out ----------
__global__ __launch_bounds__(256) void k_conv1_mfma(
    const float* __restrict__ in,  // [B][64][256][256] fp32 (feature_map)
    const float* __restrict__ w,   // [32][64][3][3]
    const float* __restrict__ bias, const float* __restrict__ g,
    const float* __restrict__ bb, const float* __restrict__ m,
    const float* __restrict__ vv,
    short* __restrict__ out) {
  constexpr int TX = 64, XT = 66;
  __shared__ short tile[4 * XT * 64];  // xor-swizzled 16B chunks
  __shared__ short wlds[9216];
  __shared__ float sc[32], sh[32];
  int tid = threadIdx.x;
  int lane = tid & 63, wid = tid >> 6;
  int b = blockIdx.z, y0 = blockIdx.y * 2, x0 = blockIdx.x * TX;
  if (tid < 32) {
    float s = g[tid] * rsqrtf(vv[tid] + 1e-5f);
    sc[tid] = s;
    sh[tid] = (bias[tid] - m[tid]) * s + bb[tid];
  }
  // stage all 64 cin, fp32 NCHW gather -> bf16 NHWC LDS (chunk-swizzled)
  for (int ir = 0; ir < 4; ++ir) {
    int gy = y0 - 1 + ir;
    bool yok = (unsigned)gy < 256u;
    for (int ch = tid; ch < XT * 8; ch += 256) {
      int xl = ch >> 3, cg = ch & 7;
      int gx = x0 - 1 + xl;
      short8 v = {0, 0, 0, 0, 0, 0, 0, 0};
      if (yok && (unsigned)gx < 256u) {
        const float* p = in + (((size_t)(b * 64 + cg * 8)) << 16) + (gy << 8) + gx;
#pragma unroll
        for (int k = 0; k < 8; ++k) v[k] = f2b(p[(size_t)k << 16]);
      }
      *(short8*)&tile[((ir * XT + xl) << 6) + ((cg ^ (xl & 7)) << 3)] = v;
    }
  }
  int px = lane & 15, g4 = lane >> 4;
  int wx = wid;
  f32x4 acc[2][2];
#pragma unroll
  for (int r = 0; r < 2; ++r)
#pragma unroll
    for (int ct = 0; ct < 2; ++ct) acc[r][ct] = {0.f, 0.f, 0.f, 0.f};
  for (int cb = 0; cb < 2; ++cb) {
    if (cb) __syncthreads();
    for (int s = tid; s < 9216; s += 256) {
      int co = s / 288, rem = s - co * 288;
      int cin = rem / 9, tap = rem - cin * 9;
      wlds[tap * 1024 + co * 32 + cin] = f2b(w[(co * 64 + cb * 32 + cin) * 9 + tap]);
    }
    __syncthreads();
    short8 wf[9][2];
#pragma unroll
    for (int tap = 0; tap < 9; ++tap)
#pragma unroll
      for (int ct = 0; ct < 2; ++ct)
        wf[tap][ct] = *(short8*)&wlds[tap * 1024 + (ct * 16 + px) * 32 + g4 * 8];
#pragma unroll
    for (int dx = 0; dx < 3; ++dx) {
      short8 fr[4];
#pragma unroll
      for (int ir = 0; ir < 4; ++ir) {
        int xl = wx * 16 + px + dx;
        fr[ir] = *(short8*)&tile[((ir * XT + xl) << 6) + (((cb * 4 + g4) ^ (xl & 7)) << 3)];
      }
#pragma unroll
      for (int dy = 0; dy < 3; ++dy)
#pragma unroll
        for (int r = 0; r < 2; ++r)
#pragma unroll
          for (int ct = 0; ct < 2; ++ct)
            acc[r][ct] = __builtin_amdgcn_mfma_f32_16x16x32_bf16(
                wf[dy * 3 + dx][ct], fr[r + dy], acc[r][ct], 0, 0, 0);
    }
  }
#pragma unroll
  for (int r = 0; r < 2; ++r) {
    int y = y0 + r;
    int xg = x0 + wx * 16 + px;
    size_t ob = (((size_t)(b * 256 + y) * 256 + xg) << 5);
#pragma unroll
    for (int ct = 0; ct < 2; ++ct) {
      unsigned short u[4];
#pragma unroll
      for (int q = 0; q < 4; ++q) {
        int co = ct * 16 + g4 * 4 + q;
        float val = acc[r][ct][q] * sc[co] + sh[co];
        val = val > 0.f ? val : 0.f;
        u[q] = (unsigned short)f2b(val);
      }
      uint2 pk;
      pk.x = (unsigned)u[0] | ((unsigned)u[1] << 16);
      pk.y = (unsigned)u[2] | ((unsigned)u[3] << 16);
      *(uint2*)(out + ob + ct * 16 + g4 * 4) = pk;
    }
  }
}

// ---------------- 2x2 avg pool, NHWC ----------------
template <int LOG>
__global__ __launch_bounds__(256) void k_pool2(const short* __restrict__ in,
                                               short* __restrict__ out) {
  int t = blockIdx.x * 256 + threadIdx.x;
  int c = t & 31;
  int r = t >> 5;
  int x = r & ((1 << LOG) - 1);
  int y = (r >> LOG) & ((1 << LOG) - 1);
  int b = r >> (2 * LOG);
  int Wi = 2 << LOG;
  size_t ib = (((size_t)(b * Wi + 2 * y) * Wi) + 2 * x) * 32 + c;
  float s = b2f(in[ib]) + b2f(in[ib + 32]) + b2f(in[ib + (size_t)Wi * 32]) +
            b2f(in[ib + (size_t)Wi * 32 + 32]);
  out[t] = f2b(0.25f * s);
}

// ---------------- global mean over 32x32, NHWC ----------------
__global__ __launch_bounds__(256) void k_gmean(const short* __restrict__ in,
                                               float* __restrict__ meanbuf) {
  int b = blockIdx.x;
  int tid = threadIdx.x;
  int c = tid & 31, pg = tid >> 5;
  float s = 0.f;
  for (int p = pg; p < 1024; p += 8)
    s += b2f(in[((size_t)b * 1024 + p) * 32 + c]);
  __shared__ float red[8][32];
  red[pg][c] = s;
  __syncthreads();
  if (tid < 32) {
    float t2 = 0.f;
#pragma unroll
    for (int k = 0; k < 8; ++k) t2 += red[k][c];
    meanbuf[b * 32 + c] = t2 * (1.f / 1024.f);
  }
}

// ---------------- fc (fp32 logits) ----------------
__global__ void k_fc(const float* __restrict__ meanbuf,
                     const float* __restrict__ fw, const float* __restrict__ fb,
                     float* __restrict__ logits) {
  int t = threadIdx.x;
  if (t < 32) {
    int b = t >> 1, o = t & 1;
    float s = fb[o];
    for (int c = 0; c < 32; ++c) s = fmaf(meanbuf[b * 32 + c], fw[o * 32 + c], s);
    logits[t] = s;
  }
}

extern "C" void kernel_launch(void* const* d_in, const int* in_sizes, int n_in,
                              void* d_out, int out_size, void* d_ws,
                              size_t ws_size, hipStream_t stream) {
  const float* x = (const float*)d_in[0];
  const float* dmean = (const float*)d_in[1];
  const float* dstd = (const float*)d_in[2];
  const float* w_spa = (const float*)d_in[3];
  const float* b_spa = (const float*)d_in[4];
  const float* w_fre = (const float*)d_in[5];
  const float* b_fre = (const float*)d_in[6];
  const float* bn0_g = (const float*)d_in[7];
  const float* bn0_b = (const float*)d_in[8];
  const float* bn0_m = (const float*)d_in[9];
  const float* bn0_v = (const float*)d_in[10];
  const float* cls_w1 = (const float*)d_in[11];
  const float* cls_b1 = (const float*)d_in[12];
  const float* cls_w = (const float*)d_in[13];
  const float* cls_b = (const float*)d_in[14];
  const float* cbn_g = (const float*)d_in[15];
  const float* cbn_b = (const float*)d_in[16];
  const float* cbn_m = (const float*)d_in[17];
  const float* cbn_v = (const float*)d_in[18];
  const float* fc_w = (const float*)d_in[19];
  const float* fc_b = (const float*)d_in[20];

  float* out = (float*)d_out;
  float* logits = out;     // [16,2] fp32
  float* feat = out + 32;  // [16,64,256,256] fp32 NCHW

  char* ws = (char*)d_ws;
  float* D = (float*)ws;                        // 256 KB
  float* M1 = (float*)(ws + (1u << 20));        // 12.6 MB
  float* xf = (float*)(ws + (16u << 20));       // 12.6 MB (all dead before convs)
  short* bufA = (short*)ws;                     // 64 MiB NHWC bf16
  short* bufB = (short*)(ws + (64u << 20));     // 64 MiB
  float* meanbuf = (float*)(ws + (64u << 20));  // at bufB base (dead after L10)

  // DCT branch (fp32, BLAS-order accumulation)
  k_build_dct<<<dim3(256), dim3(256), 0, stream>>>(D);
  k_dct1<<<dim3(8, 8, 48), dim3(256), 0, stream>>>(D, x, M1);
  k_dct2<<<dim3(8, 8, 48), dim3(256), 0, stream>>>(M1, D, dmean, dstd, xf);

  // front convs + bn0 + relu -> feature_map (output 1, fp32 NCHW)
  k_conv_front<<<dim3(128, 16, 2), dim3(256), 0, stream>>>(
      x, xf, w_spa, b_spa, w_fre, b_fre, bn0_g, bn0_b, bn0_m, bn0_v, feat);

  const int WS = 32 * 32 * 9;
  // L1 (64->32) MFMA, reads fp32 NCHW feature_map from d_out
  k_conv1_mfma<<<dim3(4, 128, 16), dim3(256), 0, stream>>>(
      feat, cls_w1, cls_b1, cbn_g, cbn_b, cbn_m, cbn_v, bufA);
  // L2..L4 @256
  k_conv_mfma<64><<<dim3(4, 128, 16), dim3(256), 0, stream>>>(
      bufA, cls_w + 0 * WS, cls_b + 0 * 32, cbn_g + 32, cbn_b + 32, cbn_m + 32,
      cbn_v + 32, bufB, 256);
  k_conv_mfma<64><<<dim3(4, 128, 16), dim3(256), 0, stream>>>(
      bufB, cls_w + 1 * WS, cls_b + 1 * 32, cbn_g + 64, cbn_b + 64, cbn_m + 64,
      cbn_v + 64, bufA, 256);
  k_conv_mfma<64><<<dim3(4, 128, 16), dim3(256), 0, stream>>>(
      bufA, cls_w + 2 * WS, cls_b + 2 * 32, cbn_g + 96, cbn_b + 96, cbn_m + 96,
      cbn_v + 96, bufB, 256);
  k_pool2<7><<<dim3(32768), dim3(256), 0, stream>>>(bufB, bufA);  // ->128
  // L5,L6 @128
  k_conv_mfma<64><<<dim3(2, 64, 16), dim3(256), 0, stream>>>(
      bufA, cls_w + 3 * WS, cls_b + 3 * 32, cbn_g + 128, cbn_b + 128,
      cbn_m + 128, cbn_v + 128, bufB, 128);
  k_conv_mfma<64><<<dim3(2, 64, 16), dim3(256), 0, stream>>>(
      bufB, cls_w + 4 * WS, cls_b + 4 * 32, cbn_g + 160, cbn_b + 160,
      cbn_m + 160, cbn_v + 160, bufA, 128);
  k_pool2<6><<<dim3(8192), dim3(256), 0, stream>>>(bufA, bufB);  // ->64
  // L7,L8 @64
  k_conv_mfma<64><<<dim3(1, 32, 16), dim3(256), 0, stream>>>(
      bufB, cls_w + 5 * WS, cls_b + 5 * 32, cbn_g + 192, cbn_b + 192,
      cbn_m + 192, cbn_v + 192, bufA, 64);
  k_conv_mfma<64><<<dim3(1, 32, 16), dim3(256), 0, stream>>>(
      bufA, cls_w + 6 * WS, cls_b + 6 * 32, cbn_g + 224, cbn_b + 224,
      cbn_m + 224, cbn_v + 224, bufB, 64);
  k_pool2<5><<<dim3(2048), dim3(256), 0, stream>>>(bufB, bufA);  // ->32
  // L9,L10 @32
  k_conv_mfma<32><<<dim3(1, 16, 16), dim3(256), 0, stream>>>(
      bufA, cls_w + 7 * WS, cls_b + 7 * 32, cbn_g + 256, cbn_b + 256,
      cbn_m + 256, cbn_v + 256, bufB, 32);
  k_conv_mfma<32><<<dim3(1, 16, 16), dim3(256), 0, stream>>>(
      bufB, cls_w + 8 * WS, cls_b + 8 * 32, cbn_g + 288, cbn_b + 288,
      cbn_m + 288, cbn_v + 288, bufA, 32);

  // global mean + fc
  k_gmean<<<dim3(16), dim3(256), 0, stream>>>(bufA, meanbuf);
  k_fc<<<dim3(1), dim3(64), 0, stream>>>(meanbuf, fc_w, fc_b, logits);
}